// Round 3
// baseline (143.588 us; speedup 1.0000x reference)
//
#include <hip/hip_runtime.h>
#include <math.h>

// StructLoss: sqrt(mean(|grads4(outputs - labels)|) + 1e-16)
// grads4 is linear -> compute on d = outputs - labels directly.
// [B=16, C=6, H=512, W=512] fp32; mean over B*4C*H*W.
//
// One 64-lane wave owns a full 512-wide row (lane l -> cols 8l..8l+7),
// walks a 4-row strip with a rolling 3-row register window of d.
// Explicit depth-2 prefetch: loads for row r+2 issue before row r+1 is
// consumed. Column neighbors via __shfl; lane 0/63 are the zero-pad edge.
// Final mean+sqrt fused via last-block atomic counter (deterministic
// fixed-order double reduction).

#define NTHREADS 256
#define STRIP 4
#define WV 512
#define HT 512
#define PLANES 96
#define WAVES_PER_PLANE (HT / STRIP)               // 128
#define TOTAL_WAVES (PLANES * WAVES_PER_PLANE)     // 12288
#define NBLOCKS (TOTAL_WAVES / (NTHREADS / 64))    // 3072

struct Raw { float4 o0, o1, l0, l1; };
struct Row { float d[8]; float eL, eR; };

__device__ __forceinline__ Raw load_raw(const float* __restrict__ ob,
                                        const float* __restrict__ lb, int r) {
    Raw w;
    const size_t off = (size_t)r * WV;
    w.o0 = *reinterpret_cast<const float4*>(ob + off);
    w.o1 = *reinterpret_cast<const float4*>(ob + off + 4);
    w.l0 = *reinterpret_cast<const float4*>(lb + off);
    w.l1 = *reinterpret_cast<const float4*>(lb + off + 4);
    return w;
}

__device__ __forceinline__ Row convert(const Raw& w, int lane) {
    Row row;
    row.d[0] = w.o0.x - w.l0.x; row.d[1] = w.o0.y - w.l0.y;
    row.d[2] = w.o0.z - w.l0.z; row.d[3] = w.o0.w - w.l0.w;
    row.d[4] = w.o1.x - w.l1.x; row.d[5] = w.o1.y - w.l1.y;
    row.d[6] = w.o1.z - w.l1.z; row.d[7] = w.o1.w - w.l1.w;
    const float up = __shfl_up(row.d[7], 1, 64);
    const float dn = __shfl_down(row.d[0], 1, 64);
    row.eL = (lane == 0) ? 0.f : up;   // col 8l-1 (image pad at lane 0)
    row.eR = (lane == 63) ? 0.f : dn;  // col 8l+8 (image pad at lane 63)
    return row;
}

__device__ __forceinline__ Row zero_row() {
    Row row;
    #pragma unroll
    for (int k = 0; k < 8; ++k) row.d[k] = 0.f;
    row.eL = 0.f; row.eR = 0.f;
    return row;
}

__global__ __launch_bounds__(NTHREADS) void struct_loss(
        const float* __restrict__ out_p, const float* __restrict__ lab_p,
        float* __restrict__ partials, unsigned* __restrict__ counter,
        float* __restrict__ out, double inv_count) {
    const int gwave = (blockIdx.x * NTHREADS + threadIdx.x) >> 6;  // 0..12287
    const int lane  = threadIdx.x & 63;
    const int plane = gwave >> 7;                  // / WAVES_PER_PLANE
    const int row0  = (gwave & (WAVES_PER_PLANE - 1)) * STRIP;

    const size_t base = (size_t)plane * (HT * WV) + lane * 8;
    const float* ob = out_p + base;
    const float* lb = lab_p + base;

    float acc = 0.f;

    // Prologue: issue 3 rows of loads before any consumption.
    Raw raw_p, raw_c, raw_n;
    const bool has_p = (row0 > 0);
    if (has_p) raw_p = load_raw(ob, lb, row0 - 1);
    raw_c = load_raw(ob, lb, row0);
    raw_n = load_raw(ob, lb, row0 + 1);            // row0+1 <= 509, always valid

    Row rp = has_p ? convert(raw_p, lane) : zero_row();
    Row rc = convert(raw_c, lane);

    #pragma unroll
    for (int rr = 0; rr < STRIP; ++rr) {
        const int r = row0 + rr;

        // Issue loads for row r+2 BEFORE consuming row r+1 (depth-2 pipeline).
        Raw raw_n2;
        const bool has_n2 = (r + 2 < HT);
        if (has_n2) raw_n2 = load_raw(ob, lb, r + 2);

        Row rn;
        if (r + 1 < HT) rn = convert(raw_n, lane); else rn = zero_row();

        #pragma unroll
        for (int k = 0; k < 8; ++k) {
            const float cL = (k > 0) ? rc.d[k - 1] : rc.eL;
            const float cR = (k < 7) ? rc.d[k + 1] : rc.eR;
            const float pL = (k > 0) ? rp.d[k - 1] : rp.eL;
            const float pR = (k < 7) ? rp.d[k + 1] : rp.eR;
            const float nL = (k > 0) ? rn.d[k - 1] : rn.eL;
            const float nR = (k < 7) ? rn.d[k + 1] : rn.eR;

            const float gy = rp.d[k] - rn.d[k];   // x[i-1,j]   - x[i+1,j]
            const float gx = cL - cR;             // x[i,j-1]   - x[i,j+1]
            const float gD = pL - nR;             // x[i-1,j-1] - x[i+1,j+1]
            const float gd = pR - nL;             // x[i-1,j+1] - x[i+1,j-1]
            acc += fabsf(gy) + fabsf(gx) + fabsf(gD) + fabsf(gd);
        }
        rp = rc;
        rc = rn;
        raw_n = raw_n2;
    }

    // 64-lane wave reduce
    #pragma unroll
    for (int off = 32; off > 0; off >>= 1)
        acc += __shfl_down(acc, off, 64);

    __shared__ float smem[NTHREADS / 64];
    const int wid = threadIdx.x >> 6;
    if (lane == 0) smem[wid] = acc;
    __syncthreads();

    __shared__ bool amLast;
    if (threadIdx.x == 0) {
        float s = 0.f;
        #pragma unroll
        for (int w = 0; w < NTHREADS / 64; ++w) s += smem[w];
        partials[blockIdx.x] = s;
        __threadfence();                       // publish partial
        const unsigned old = atomicAdd(counter, 1u);
        amLast = (old == (unsigned)(NBLOCKS - 1));
    }
    __syncthreads();

    if (amLast) {
        __threadfence();                       // see all partials
        double s = 0.0;
        for (int i = threadIdx.x; i < NBLOCKS; i += NTHREADS)
            s += (double)partials[i];
        #pragma unroll
        for (int off = 32; off > 0; off >>= 1)
            s += __shfl_down(s, off, 64);
        __shared__ double dsm[NTHREADS / 64];
        if (lane == 0) dsm[wid] = s;
        __syncthreads();
        if (threadIdx.x == 0) {
            double t = 0.0;
            #pragma unroll
            for (int w = 0; w < NTHREADS / 64; ++w) t += dsm[w];
            out[0] = (float)sqrt(t * inv_count + 1e-16);
        }
    }
}

extern "C" void kernel_launch(void* const* d_in, const int* in_sizes, int n_in,
                              void* d_out, int out_size, void* d_ws, size_t ws_size,
                              hipStream_t stream) {
    const float* outputs = (const float*)d_in[0];
    const float* labels  = (const float*)d_in[1];
    float* out = (float*)d_out;

    unsigned* counter = (unsigned*)d_ws;               // 1 u32 at offset 0
    float* partials   = (float*)d_ws + 16;             // NBLOCKS floats, 64B-offset

    const double inv_count = 1.0 / (16.0 * 24.0 * 512.0 * 512.0);

    hipMemsetAsync(counter, 0, sizeof(unsigned), stream);
    struct_loss<<<NBLOCKS, NTHREADS, 0, stream>>>(outputs, labels, partials,
                                                  counter, out, inv_count);
}

// Round 4
// 42.170 us; speedup vs baseline: 3.4050x; 3.4050x over previous
//
#include <hip/hip_runtime.h>
#include <math.h>

// StructLoss: sqrt(mean(|grads4(outputs - labels)|) + 1e-16)
// grads4 linear -> compute on d = outputs - labels.
// [B=16, C=6, H=512, W=512] fp32; mean over B*4C*H*W.
//
// Block = one 16x512 tile. Stage phase: 18 halo rows of d into LDS via 18
// independent float4 loads/thread (clamped+masked, branchless). Compute
// phase: per-wave 4-row rolling window from LDS (2x ds_read_b128 + 2 shfl
// per row, zero conditionals). Two-kernel deterministic reduction.

#define NTHREADS 256
#define TROWS 16
#define SROWS (TROWS + 2)                      // 18 staged rows
#define WV 512
#define HT 512
#define PLANES 96
#define STRIPS (HT / TROWS)                    // 32
#define NBLOCKS (PLANES * STRIPS)              // 3072
#define F4_PER_TILE (SROWS * WV / 4)           // 2304
#define LD_PER_THREAD (F4_PER_TILE / NTHREADS) // 9

struct Row { float d[8]; float eL, eR; };

__device__ __forceinline__ Row lds_row(const float* __restrict__ sd,
                                       int sr, int lane) {
    Row row;
    const float4 a = *reinterpret_cast<const float4*>(sd + sr * WV + lane * 8);
    const float4 b = *reinterpret_cast<const float4*>(sd + sr * WV + lane * 8 + 4);
    row.d[0] = a.x; row.d[1] = a.y; row.d[2] = a.z; row.d[3] = a.w;
    row.d[4] = b.x; row.d[5] = b.y; row.d[6] = b.z; row.d[7] = b.w;
    const float up = __shfl_up(row.d[7], 1, 64);
    const float dn = __shfl_down(row.d[0], 1, 64);
    row.eL = (lane == 0)  ? 0.f : up;   // col 8l-1 (image zero-pad at lane 0)
    row.eR = (lane == 63) ? 0.f : dn;   // col 8l+8 (image zero-pad at lane 63)
    return row;
}

__global__ __launch_bounds__(NTHREADS, 4) void struct_loss_partial(
        const float* __restrict__ out_p, const float* __restrict__ lab_p,
        float* __restrict__ partials) {
    __shared__ float sd[SROWS * WV];           // 36,864 B

    const int plane = blockIdx.x >> 5;         // / STRIPS
    const int strip = blockIdx.x & (STRIPS - 1);
    const int row0  = strip * TROWS;
    const size_t pbase = (size_t)plane * (HT * WV);

    // ---- stage: d for global rows row0-1 .. row0+16 (clamped + masked) ----
    float4 ov[LD_PER_THREAD], lv[LD_PER_THREAD];
    #pragma unroll
    for (int k = 0; k < LD_PER_THREAD; ++k) {
        const int p  = threadIdx.x + NTHREADS * k;  // float4 slot in tile
        const int r  = p >> 7;                      // 128 float4 per row
        const int c4 = p & 127;
        const int gr = row0 + r - 1;
        const int grc = min(max(gr, 0), HT - 1);    // clamp -> always valid addr
        const size_t goff = pbase + (size_t)grc * WV + c4 * 4;
        ov[k] = *reinterpret_cast<const float4*>(out_p + goff);
        lv[k] = *reinterpret_cast<const float4*>(lab_p + goff);
    }
    #pragma unroll
    for (int k = 0; k < LD_PER_THREAD; ++k) {
        const int p = threadIdx.x + NTHREADS * k;
        const int r = p >> 7;
        const int gr = row0 + r - 1;
        const float m = (gr >= 0 && gr < HT) ? 1.f : 0.f;  // zero-pad halo
        float4 d;
        d.x = m * (ov[k].x - lv[k].x);
        d.y = m * (ov[k].y - lv[k].y);
        d.z = m * (ov[k].z - lv[k].z);
        d.w = m * (ov[k].w - lv[k].w);
        *reinterpret_cast<float4*>(sd + (size_t)p * 4) = d;
    }
    __syncthreads();

    // ---- compute: wave w owns tile rows 4w..4w+3 (staged rows 4w+1..4w+4)
    const int wv   = threadIdx.x >> 6;
    const int lane = threadIdx.x & 63;
    float acc = 0.f;

    Row rp = lds_row(sd, wv * 4,     lane);
    Row rc = lds_row(sd, wv * 4 + 1, lane);
    #pragma unroll
    for (int rr = 0; rr < 4; ++rr) {
        Row rn = lds_row(sd, wv * 4 + 2 + rr, lane);

        #pragma unroll
        for (int k = 0; k < 8; ++k) {
            const float cL = (k > 0) ? rc.d[k - 1] : rc.eL;
            const float cR = (k < 7) ? rc.d[k + 1] : rc.eR;
            const float pL = (k > 0) ? rp.d[k - 1] : rp.eL;
            const float pR = (k < 7) ? rp.d[k + 1] : rp.eR;
            const float nL = (k > 0) ? rn.d[k - 1] : rn.eL;
            const float nR = (k < 7) ? rn.d[k + 1] : rn.eR;

            const float gy = rp.d[k] - rn.d[k];   // x[i-1,j]   - x[i+1,j]
            const float gx = cL - cR;             // x[i,j-1]   - x[i,j+1]
            const float gD = pL - nR;             // x[i-1,j-1] - x[i+1,j+1]
            const float gd = pR - nL;             // x[i-1,j+1] - x[i+1,j-1]
            acc += fabsf(gy) + fabsf(gx) + fabsf(gD) + fabsf(gd);
        }
        rp = rc;
        rc = rn;
    }

    // ---- block reduction ----
    #pragma unroll
    for (int off = 32; off > 0; off >>= 1)
        acc += __shfl_down(acc, off, 64);

    __shared__ float smem[NTHREADS / 64];
    if (lane == 0) smem[wv] = acc;
    __syncthreads();
    if (threadIdx.x == 0) {
        float s = 0.f;
        #pragma unroll
        for (int w = 0; w < NTHREADS / 64; ++w) s += smem[w];
        partials[blockIdx.x] = s;
    }
}

__global__ __launch_bounds__(256) void struct_loss_final(
        const float* __restrict__ partial, float* __restrict__ out,
        int nparts, double inv_count) {
    double acc = 0.0;
    for (int i = threadIdx.x; i < nparts; i += blockDim.x)
        acc += (double)partial[i];
    #pragma unroll
    for (int off = 32; off > 0; off >>= 1)
        acc += __shfl_down(acc, off, 64);
    __shared__ double smem[4];
    const int lane = threadIdx.x & 63;
    const int wid  = threadIdx.x >> 6;
    if (lane == 0) smem[wid] = acc;
    __syncthreads();
    if (threadIdx.x == 0) {
        double s = smem[0] + smem[1] + smem[2] + smem[3];
        out[0] = (float)sqrt(s * inv_count + 1e-16);
    }
}

extern "C" void kernel_launch(void* const* d_in, const int* in_sizes, int n_in,
                              void* d_out, int out_size, void* d_ws, size_t ws_size,
                              hipStream_t stream) {
    const float* outputs = (const float*)d_in[0];
    const float* labels  = (const float*)d_in[1];
    float* out = (float*)d_out;
    float* partials = (float*)d_ws;   // NBLOCKS floats

    const double inv_count = 1.0 / (16.0 * 24.0 * 512.0 * 512.0);

    struct_loss_partial<<<NBLOCKS, NTHREADS, 0, stream>>>(outputs, labels, partials);
    struct_loss_final<<<1, 256, 0, stream>>>(partials, out, NBLOCKS, inv_count);
}